// Round 1
// baseline (686.629 us; speedup 1.0000x reference)
//
#include <hip/hip_runtime.h>
#include <hip/hip_bf16.h>

typedef __bf16 bf16;
typedef __bf16 bf16x8 __attribute__((ext_vector_type(8)));
typedef __bf16 bf16x4v __attribute__((ext_vector_type(4)));
typedef float f32x4 __attribute__((ext_vector_type(4)));

#define DEV static __device__ __forceinline__

DEV void gll16(const void* g, void* l) {
  __builtin_amdgcn_global_load_lds((__attribute__((address_space(1))) void*)g,
                                   (__attribute__((address_space(3))) void*)l,
                                   16, 0, 0);
}

DEV bf16 tobf(float f) { return (bf16)f; }

// ---------------- cast f32 -> bf16 (x4 vectorized) ----------------
__global__ void cast_f2b_kernel(const float* __restrict__ in, bf16* __restrict__ out, int n4) {
  int i = blockIdx.x * 256 + threadIdx.x;
  if (i < n4) {
    const float4 v = ((const float4*)in)[i];
    bf16x4v o;
    o[0] = tobf(v.x); o[1] = tobf(v.y); o[2] = tobf(v.z); o[3] = tobf(v.w);
    ((bf16x4v*)out)[i] = o;
  }
}

// ------------- transpose-pack: out[N][K] bf16 = in[K][N] f32 * scale -------------
// batched over blockIdx.z with element strides in_hs/out_hs (0 for non-batched)
__global__ __launch_bounds__(256)
void tpack_kernel(const float* __restrict__ in, bf16* __restrict__ out,
                  int K, int N, int in_hs, int out_hs, float scale) {
  __shared__ float tile[32][33];
  const int k0 = blockIdx.x << 5, n0 = blockIdx.y << 5;
  const float* ip = in + (size_t)blockIdx.z * in_hs;
  bf16* op = out + (size_t)blockIdx.z * out_hs;
  const int tx = threadIdx.x & 31, ty = threadIdx.x >> 5;
#pragma unroll
  for (int r = 0; r < 4; ++r)
    tile[ty * 4 + r][tx] = ip[(size_t)(k0 + ty * 4 + r) * N + n0 + tx];
  __syncthreads();
#pragma unroll
  for (int r = 0; r < 4; ++r)
    op[(size_t)(n0 + ty * 4 + r) * K + k0 + tx] = tobf(tile[tx][ty * 4 + r] * scale);
}

// ---------------- bias scale copy ----------------
__global__ void bscale_kernel(const float* __restrict__ in, float* __restrict__ out, int n, float s) {
  int i = blockIdx.x * 256 + threadIdx.x;
  if (i < n) out[i] = in[i] * s;
}

// =====================================================================
// GEMM: out[M][N] = A[M][K] (bf16, row-major) dot W[N][K] (bf16, row-major, = B^T)
// EPI 0: bf16 out = acc + bias
// EPI 1: f32  out = acc + bias + resid
// EPI 2: bf16 out = relu(acc + bias)
// EPI 3: bf16 V-transpose store: out[((b*16+h)*64+dk)*1024 + l] (M rows = b*1024+l, cols = h*64+dk)
// BM=BN=128, BK=64, 256 threads (4 waves, 2x2), double-buffered global_load_lds,
// XOR swizzle ((row&7)<<4 bytes) applied on stage-source and read side.
// =====================================================================
template<int EPI>
__global__ __launch_bounds__(256, 2)
void gemm_bt(const bf16* __restrict__ A, const bf16* __restrict__ W,
             const float* __restrict__ bias, const float* __restrict__ resid,
             void* __restrict__ outv, int M, int N, int K) {
  __shared__ bf16 sA[2][128 * 64];
  __shared__ bf16 sB[2][128 * 64];
  const int nbx = N >> 7;
  const int nwg = (M >> 7) * nbx;
  int bid = (int)blockIdx.x;
  bid = (bid & 7) * (nwg >> 3) + (bid >> 3);   // XCD swizzle (nwg % 8 == 0 for all our shapes)
  const int tm = bid / nbx, tn = bid - tm * nbx;
  const int tid = threadIdx.x;
  const int lane = tid & 63;
  const int w = tid >> 6;
  const int wm = (w >> 1) << 6, wn = (w & 1) << 6;
  const int l15 = lane & 15, l4 = lane >> 4;

  // staging granules: g = tid + j*256 covers 1024 granules (128 rows x 8 x 16B)
  int srow[4], scol[4];
#pragma unroll
  for (int j = 0; j < 4; ++j) {
    int g = tid + (j << 8);
    srow[j] = g >> 3;
    scol[j] = ((g & 7) ^ (srow[j] & 7)) << 3;  // element offset of swizzled source granule
  }
  const bf16* Abase = A + (size_t)(tm * 128) * K;
  const bf16* Bbase = W + (size_t)(tn * 128) * K;

  f32x4 acc[4][4] = {};

  const int nt = K >> 6;
  int cur = 0;

  auto stage = [&](int buf, int t) {
    const int kb = t << 6;
#pragma unroll
    for (int j = 0; j < 4; ++j) {
      int g = tid + (j << 8);
      gll16(Abase + (size_t)srow[j] * K + kb + scol[j], &sA[buf][g << 3]);
    }
#pragma unroll
    for (int j = 0; j < 4; ++j) {
      int g = tid + (j << 8);
      gll16(Bbase + (size_t)srow[j] * K + kb + scol[j], &sB[buf][g << 3]);
    }
  };

  stage(0, 0);
  __syncthreads();

  for (int t = 0; t < nt; ++t) {
    if (t + 1 < nt) stage(cur ^ 1, t + 1);
    bf16x8 af[4][2], bfm[4][2];
#pragma unroll
    for (int mi = 0; mi < 4; ++mi)
#pragma unroll
      for (int kk = 0; kk < 2; ++kk) {
        int r = wm + (mi << 4) + l15;
        int off = (r << 7) + (kk << 6) + (l4 << 4);
        off ^= (r & 7) << 4;
        af[mi][kk] = *(const bf16x8*)((const char*)sA[cur] + off);
      }
#pragma unroll
    for (int ni = 0; ni < 4; ++ni)
#pragma unroll
      for (int kk = 0; kk < 2; ++kk) {
        int r = wn + (ni << 4) + l15;
        int off = (r << 7) + (kk << 6) + (l4 << 4);
        off ^= (r & 7) << 4;
        bfm[ni][kk] = *(const bf16x8*)((const char*)sB[cur] + off);
      }
#pragma unroll
    for (int mi = 0; mi < 4; ++mi)
#pragma unroll
      for (int ni = 0; ni < 4; ++ni)
#pragma unroll
        for (int kk = 0; kk < 2; ++kk)
          acc[mi][ni] = __builtin_amdgcn_mfma_f32_16x16x32_bf16(af[mi][kk], bfm[ni][kk],
                                                                acc[mi][ni], 0, 0, 0);
    __syncthreads();
    cur ^= 1;
  }

  // ---------- epilogue ----------
  const int row0 = tm * 128 + wm + (l4 << 2);
  const int col0 = tn * 128 + wn + l15;
#pragma unroll
  for (int ni = 0; ni < 4; ++ni) {
    const int col = col0 + (ni << 4);
    const float bv = bias ? bias[col] : 0.f;
#pragma unroll
    for (int mi = 0; mi < 4; ++mi) {
      const int rr = row0 + (mi << 4);
      f32x4 v = acc[mi][ni];
      if (EPI == 0) {
        bf16* out = (bf16*)outv;
#pragma unroll
        for (int r = 0; r < 4; ++r) out[(size_t)(rr + r) * N + col] = tobf(v[r] + bv);
      } else if (EPI == 1) {
        float* out = (float*)outv;
#pragma unroll
        for (int r = 0; r < 4; ++r) {
          size_t idx = (size_t)(rr + r) * N + col;
          out[idx] = v[r] + bv + resid[idx];
        }
      } else if (EPI == 2) {
        bf16* out = (bf16*)outv;
#pragma unroll
        for (int r = 0; r < 4; ++r) out[(size_t)(rr + r) * N + col] = tobf(fmaxf(v[r] + bv, 0.f));
      } else { // EPI == 3: V^T store
        bf16* out = (bf16*)outv;
        const int bb = rr >> 10, l0 = rr & 1023;
        const int hh = col >> 6, dk = col & 63;
        bf16x4v pk;
#pragma unroll
        for (int r = 0; r < 4; ++r) pk[r] = tobf(v[r] + bv);
        *(bf16x4v*)(out + ((size_t)((bb * 16 + hh) * 64 + dk) << 10) + l0) = pk;
      }
    }
  }
}

// =====================================================================
// Attention: per (b,h), Q-tile 128 rows (4 waves x 32), KV tiles of 64.
// Q: [B][1024][16][64] bf16 (pre-scaled by 1/8 incl bias), K same, Vt: [B][16][64][1024].
// Softmax denominator over ALL columns (reference applies tril AFTER softmax);
// mask zeroes only the PV numerator.
// =====================================================================
template<bool MASKED>
__global__ __launch_bounds__(256, 2)
void attn_kernel(const bf16* __restrict__ Qp, const bf16* __restrict__ Kp,
                 const bf16* __restrict__ Vt, bf16* __restrict__ Z) {
  __shared__ bf16 sK[64 * 64];
  __shared__ bf16 sV[64 * 64];
  __shared__ bf16 sP[4][32 * 72];
  const int Lk = 1024;
  const int bh = blockIdx.y, b = bh >> 4, h = bh & 15;
  const int q0 = blockIdx.x << 7;
  const int tid = threadIdx.x, lane = tid & 63, w = tid >> 6;
  const int l15 = lane & 15, l4 = lane >> 4;

  const bf16* Qb = Qp + ((size_t)(b * 1024 + q0 + w * 32)) * 1024 + h * 64;
  bf16x8 qf[2][2];
#pragma unroll
  for (int mi = 0; mi < 2; ++mi)
#pragma unroll
    for (int kk = 0; kk < 2; ++kk)
      qf[mi][kk] = *(const bf16x8*)(Qb + (size_t)((mi << 4) + l15) * 1024 + (kk << 5) + (l4 << 3));

  f32x4 o[4][2] = {};
  float Mr[2][4], Lr[2][4];
#pragma unroll
  for (int mi = 0; mi < 2; ++mi)
#pragma unroll
    for (int r = 0; r < 4; ++r) { Mr[mi][r] = -1e30f; Lr[mi][r] = 0.f; }

  const bf16* Kb = Kp + ((size_t)b * Lk) * 1024 + h * 64;
  const bf16* Vb = Vt + ((size_t)(b * 16 + h)) * 64 * Lk;

  for (int t = 0; t < (Lk >> 6); ++t) {
    const int kv0 = t << 6;
    __syncthreads();  // previous tile fully consumed
#pragma unroll
    for (int j = 0; j < 2; ++j) {
      int g = tid + (j << 8);
      int r = g >> 3;
      int sc = ((g & 7) ^ (r & 7)) << 3;
      gll16(Kb + (size_t)(kv0 + r) * 1024 + sc, &sK[g << 3]);
      gll16(Vb + (size_t)r * Lk + kv0 + sc, &sV[g << 3]);
    }
    __syncthreads();  // drains vmcnt (global_load_lds) per barrier semantics

    // S = Q K^T (pre-scaled)
    bf16x8 kf[4][2];
#pragma unroll
    for (int n = 0; n < 4; ++n)
#pragma unroll
      for (int kk = 0; kk < 2; ++kk) {
        int r = (n << 4) + l15;
        int off = (r << 7) + (kk << 6) + (l4 << 4);
        off ^= (r & 7) << 4;
        kf[n][kk] = *(const bf16x8*)((const char*)sK + off);
      }
    f32x4 s[4][2] = {};
#pragma unroll
    for (int n = 0; n < 4; ++n)
#pragma unroll
      for (int mi = 0; mi < 2; ++mi)
#pragma unroll
        for (int kk = 0; kk < 2; ++kk)
          s[n][mi] = __builtin_amdgcn_mfma_f32_16x16x32_bf16(qf[mi][kk], kf[n][kk],
                                                             s[n][mi], 0, 0, 0);

    // online softmax (wave-parallel, 16-lane butterflies; denominator unmasked)
#pragma unroll
    for (int mi = 0; mi < 2; ++mi)
#pragma unroll
      for (int r = 0; r < 4; ++r) {
        float tmx = fmaxf(fmaxf(s[0][mi][r], s[1][mi][r]), fmaxf(s[2][mi][r], s[3][mi][r]));
#pragma unroll
        for (int d = 1; d < 16; d <<= 1) tmx = fmaxf(tmx, __shfl_xor(tmx, d, 64));
        const float Mn = fmaxf(Mr[mi][r], tmx);
        const float al = __expf(Mr[mi][r] - Mn);
        float rs = 0.f;
#pragma unroll
        for (int n = 0; n < 4; ++n) {
          float p = __expf(s[n][mi][r] - Mn);
          s[n][mi][r] = p;
          rs += p;
        }
#pragma unroll
        for (int d = 1; d < 16; d <<= 1) rs += __shfl_xor(rs, d, 64);
        Lr[mi][r] = Lr[mi][r] * al + rs;
        Mr[mi][r] = Mn;
#pragma unroll
        for (int nd = 0; nd < 4; ++nd) o[nd][mi][r] *= al;
      }

    // write P (masked) to per-wave LDS, padded rows [32][72]
#pragma unroll
    for (int n = 0; n < 4; ++n)
#pragma unroll
      for (int mi = 0; mi < 2; ++mi)
#pragma unroll
        for (int r = 0; r < 4; ++r) {
          float v = s[n][mi][r];
          if (MASKED) {
            int cg = kv0 + (n << 4) + l15;
            int rg = q0 + (w << 5) + (mi << 4) + (l4 << 2) + r;
            if (cg > rg) v = 0.f;
          }
          sP[w][((mi << 4) + (l4 << 2) + r) * 72 + (n << 4) + l15] = tobf(v);
        }
    __syncthreads();

    // O += P V  (A = P rows q, B^T = Vt rows dk)
    bf16x8 vf[4][2], pa[2][2];
#pragma unroll
    for (int nd = 0; nd < 4; ++nd)
#pragma unroll
      for (int kk = 0; kk < 2; ++kk) {
        int r = (nd << 4) + l15;
        int off = (r << 7) + (kk << 6) + (l4 << 4);
        off ^= (r & 7) << 4;
        vf[nd][kk] = *(const bf16x8*)((const char*)sV + off);
      }
#pragma unroll
    for (int mi = 0; mi < 2; ++mi)
#pragma unroll
      for (int kk = 0; kk < 2; ++kk)
        pa[mi][kk] = *(const bf16x8*)((const char*)sP[w] +
                                      ((mi << 4) + l15) * 144 + (kk << 6) + (l4 << 4));
#pragma unroll
    for (int nd = 0; nd < 4; ++nd)
#pragma unroll
      for (int mi = 0; mi < 2; ++mi)
#pragma unroll
        for (int kk = 0; kk < 2; ++kk)
          o[nd][mi] = __builtin_amdgcn_mfma_f32_16x16x32_bf16(pa[mi][kk], vf[nd][kk],
                                                              o[nd][mi], 0, 0, 0);
  }

  // normalize + store Z [B][L][H*64]
  float inv[2][4];
#pragma unroll
  for (int mi = 0; mi < 2; ++mi)
#pragma unroll
    for (int r = 0; r < 4; ++r) inv[mi][r] = 1.f / Lr[mi][r];
  bf16* Zb = Z + ((size_t)(b * 1024 + q0 + w * 32)) * 1024 + h * 64;
#pragma unroll
  for (int nd = 0; nd < 4; ++nd)
#pragma unroll
    for (int mi = 0; mi < 2; ++mi)
#pragma unroll
      for (int r = 0; r < 4; ++r)
        Zb[(size_t)((mi << 4) + (l4 << 2) + r) * 1024 + (nd << 4) + l15] =
            tobf(o[nd][mi][r] * inv[mi][r]);
}

// ---------------- LayerNorm over D=1024, one row per block ----------------
__global__ __launch_bounds__(256)
void ln_kernel(const float* __restrict__ in, const float* __restrict__ gw,
               const float* __restrict__ bw, float* __restrict__ outf,
               bf16* __restrict__ outb) {
  const int row = blockIdx.x, tid = threadIdx.x;
  const size_t base = (size_t)row << 10;
  const float4 v = *(const float4*)(in + base + tid * 4);
  float s = v.x + v.y + v.z + v.w;
  float ss = v.x * v.x + v.y * v.y + v.z * v.z + v.w * v.w;
#pragma unroll
  for (int d = 1; d < 64; d <<= 1) { s += __shfl_xor(s, d, 64); ss += __shfl_xor(ss, d, 64); }
  __shared__ float red[8];
  const int w = tid >> 6;
  if ((tid & 63) == 0) { red[w] = s; red[4 + w] = ss; }
  __syncthreads();
  s = red[0] + red[1] + red[2] + red[3];
  ss = red[4] + red[5] + red[6] + red[7];
  const float mu = s * (1.f / 1024.f);
  const float var = ss * (1.f / 1024.f) - mu * mu;
  const float rstd = rsqrtf(var + 1e-5f);
  const float4 g4 = *(const float4*)(gw + tid * 4);
  const float4 b4 = *(const float4*)(bw + tid * 4);
  const float o0 = (v.x - mu) * rstd * g4.x + b4.x;
  const float o1 = (v.y - mu) * rstd * g4.y + b4.y;
  const float o2 = (v.z - mu) * rstd * g4.z + b4.z;
  const float o3 = (v.w - mu) * rstd * g4.w + b4.w;
  if (outf) { float4 of; of.x = o0; of.y = o1; of.z = o2; of.w = o3;
              *(float4*)(outf + base + tid * 4) = of; }
  if (outb) { bf16x4v ob; ob[0] = tobf(o0); ob[1] = tobf(o1); ob[2] = tobf(o2); ob[3] = tobf(o3);
              *(bf16x4v*)(outb + base + tid * 4) = ob; }
}

// =====================================================================
extern "C" void kernel_launch(void* const* d_in, const int* in_sizes, int n_in,
                              void* d_out, int out_size, void* d_ws, size_t ws_size,
                              hipStream_t stream) {
  const float* x   = (const float*)d_in[0];
  const float* enc = (const float*)d_in[1];
  const float* Wq1 = (const float*)d_in[2];
  const float* bq1 = (const float*)d_in[3];
  const float* Wk1 = (const float*)d_in[4];
  const float* bk1 = (const float*)d_in[5];
  const float* Wv1 = (const float*)d_in[6];
  const float* bv1 = (const float*)d_in[7];
  const float* Wo1 = (const float*)d_in[8];
  const float* bo1 = (const float*)d_in[9];
  const float* Wq2 = (const float*)d_in[10];
  const float* bq2 = (const float*)d_in[11];
  const float* Wk2 = (const float*)d_in[12];
  const float* bk2 = (const float*)d_in[13];
  const float* Wv2 = (const float*)d_in[14];
  const float* bv2 = (const float*)d_in[15];
  const float* Wo2 = (const float*)d_in[16];
  const float* bo2 = (const float*)d_in[17];
  const float* W1  = (const float*)d_in[18];
  const float* b1  = (const float*)d_in[19];
  const float* W2  = (const float*)d_in[20];
  const float* b2  = (const float*)d_in[21];
  const float* g1  = (const float*)d_in[22];
  const float* be1 = (const float*)d_in[23];
  const float* g2  = (const float*)d_in[24];
  const float* be2 = (const float*)d_in[25];
  const float* g3  = (const float*)d_in[26];
  const float* be3 = (const float*)d_in[27];

  char* ws = (char*)d_ws;
  size_t off = 0;
  auto alloc = [&](size_t bytes) { char* p = ws + off; off += (bytes + 255) & ~(size_t)255; return p; };
  const size_t ACT = (size_t)8 * 1024 * 1024 * 2;  // 16 MB: bf16 [8192][1024]
  const size_t WSQ = (size_t)1024 * 1024 * 2;      // 2 MB

  bf16* xb    = (bf16*)alloc(ACT);
  bf16* encb  = (bf16*)alloc(ACT);
  bf16* Wq1t  = (bf16*)alloc(WSQ);
  bf16* Wk1t  = (bf16*)alloc(WSQ);
  bf16* Wv1t  = (bf16*)alloc(WSQ);
  bf16* Wq2t  = (bf16*)alloc(WSQ);
  bf16* Wk2t  = (bf16*)alloc(WSQ);
  bf16* Wv2t  = (bf16*)alloc(WSQ);
  bf16* Wo1t  = (bf16*)alloc(WSQ);
  bf16* Wo2t  = (bf16*)alloc(WSQ);
  bf16* W1t   = (bf16*)alloc((size_t)4096 * 1024 * 2);
  bf16* W2t   = (bf16*)alloc((size_t)4096 * 1024 * 2);
  float* sbq1 = (float*)alloc(4096);
  float* sbq2 = (float*)alloc(4096);
  char*  S    = alloc((size_t)64 * 1024 * 1024);
  float* rbuf = (float*)alloc((size_t)8 * 1024 * 1024 * 4);
  float* xnf  = (float*)alloc((size_t)8 * 1024 * 1024 * 4);
  bf16*  xnb  = (bf16*)alloc(ACT);

  bf16* q1   = (bf16*)(S);
  bf16* k1   = (bf16*)(S + ACT);
  bf16* vt1  = (bf16*)(S + 2 * ACT);
  bf16* z1   = (bf16*)(S + 3 * ACT);
  bf16* hbuf = (bf16*)S;  // stage 3 reuse (64 MB)

  dim3 b256(256);
  // prep: casts + weight packs
  cast_f2b_kernel<<<8192, b256, 0, stream>>>(x, xb, 2097152);
  cast_f2b_kernel<<<8192, b256, 0, stream>>>(enc, encb, 2097152);
  tpack_kernel<<<dim3(32, 2, 16), b256, 0, stream>>>(Wq1, Wq1t, 1024, 64, 65536, 65536, 0.125f);
  tpack_kernel<<<dim3(32, 2, 16), b256, 0, stream>>>(Wk1, Wk1t, 1024, 64, 65536, 65536, 1.f);
  tpack_kernel<<<dim3(32, 2, 16), b256, 0, stream>>>(Wv1, Wv1t, 1024, 64, 65536, 65536, 1.f);
  tpack_kernel<<<dim3(32, 2, 16), b256, 0, stream>>>(Wq2, Wq2t, 1024, 64, 65536, 65536, 0.125f);
  tpack_kernel<<<dim3(32, 2, 16), b256, 0, stream>>>(Wk2, Wk2t, 1024, 64, 65536, 65536, 1.f);
  tpack_kernel<<<dim3(32, 2, 16), b256, 0, stream>>>(Wv2, Wv2t, 1024, 64, 65536, 65536, 1.f);
  tpack_kernel<<<dim3(32, 32, 1), b256, 0, stream>>>(Wo1, Wo1t, 1024, 1024, 0, 0, 1.f);
  tpack_kernel<<<dim3(32, 32, 1), b256, 0, stream>>>(Wo2, Wo2t, 1024, 1024, 0, 0, 1.f);
  tpack_kernel<<<dim3(32, 128, 1), b256, 0, stream>>>(W1, W1t, 1024, 4096, 0, 0, 1.f);
  tpack_kernel<<<dim3(128, 32, 1), b256, 0, stream>>>(W2, W2t, 4096, 1024, 0, 0, 1.f);
  bscale_kernel<<<4, b256, 0, stream>>>(bq1, sbq1, 1024, 0.125f);
  bscale_kernel<<<4, b256, 0, stream>>>(bq2, sbq2, 1024, 0.125f);

  // stage 1: masked self-attention
  gemm_bt<0><<<512, b256, 0, stream>>>(xb, Wq1t, sbq1, nullptr, q1, 8192, 1024, 1024);
  gemm_bt<0><<<512, b256, 0, stream>>>(xb, Wk1t, bk1, nullptr, k1, 8192, 1024, 1024);
  gemm_bt<3><<<512, b256, 0, stream>>>(xb, Wv1t, bv1, nullptr, vt1, 8192, 1024, 1024);
  attn_kernel<true><<<dim3(8, 128), b256, 0, stream>>>(q1, k1, vt1, z1);
  gemm_bt<1><<<512, b256, 0, stream>>>(z1, Wo1t, bo1, x, rbuf, 8192, 1024, 1024);
  ln_kernel<<<8192, b256, 0, stream>>>(rbuf, g1, be1, xnf, xnb);

  // stage 2: cross-attention
  gemm_bt<0><<<512, b256, 0, stream>>>(xnb, Wq2t, sbq2, nullptr, q1, 8192, 1024, 1024);
  gemm_bt<0><<<512, b256, 0, stream>>>(encb, Wk2t, bk2, nullptr, k1, 8192, 1024, 1024);
  gemm_bt<3><<<512, b256, 0, stream>>>(encb, Wv2t, bv2, nullptr, vt1, 8192, 1024, 1024);
  attn_kernel<false><<<dim3(8, 128), b256, 0, stream>>>(q1, k1, vt1, z1);
  gemm_bt<1><<<512, b256, 0, stream>>>(z1, Wo2t, bo2, xnf, rbuf, 8192, 1024, 1024);
  ln_kernel<<<8192, b256, 0, stream>>>(rbuf, g2, be2, xnf, xnb);

  // stage 3: MLP (conv1d k=1 pair)
  gemm_bt<2><<<2048, b256, 0, stream>>>(xnb, W1t, b1, nullptr, hbuf, 8192, 4096, 1024);
  gemm_bt<1><<<512, b256, 0, stream>>>(hbuf, W2t, b2, xnf, rbuf, 8192, 1024, 4096);
  ln_kernel<<<8192, b256, 0, stream>>>(rbuf, g3, be3, (float*)d_out, nullptr);
}

// Round 2
// 664.021 us; speedup vs baseline: 1.0340x; 1.0340x over previous
//
#include <hip/hip_runtime.h>
#include <hip/hip_bf16.h>

typedef __bf16 bf16;
typedef __bf16 bf16x8 __attribute__((ext_vector_type(8)));
typedef __bf16 bf16x4v __attribute__((ext_vector_type(4)));
typedef float f32x4 __attribute__((ext_vector_type(4)));

#define DEV static __device__ __forceinline__

DEV void gll16(const void* g, void* l) {
  __builtin_amdgcn_global_load_lds((__attribute__((address_space(1))) void*)g,
                                   (__attribute__((address_space(3))) void*)l,
                                   16, 0, 0);
}

DEV bf16 tobf(float f) { return (bf16)f; }

// ---------------- cast f32 -> bf16 (x4 vectorized) ----------------
__global__ void cast_f2b_kernel(const float* __restrict__ in, bf16* __restrict__ out, int n4) {
  int i = blockIdx.x * 256 + threadIdx.x;
  if (i < n4) {
    const float4 v = ((const float4*)in)[i];
    bf16x4v o;
    o[0] = tobf(v.x); o[1] = tobf(v.y); o[2] = tobf(v.z); o[3] = tobf(v.w);
    ((bf16x4v*)out)[i] = o;
  }
}

// ------------- transpose-pack: out[N][K] bf16 = in[K][N] f32 * scale -------------
__global__ __launch_bounds__(256)
void tpack_kernel(const float* __restrict__ in, bf16* __restrict__ out,
                  int K, int N, int in_hs, int out_hs, float scale) {
  __shared__ float tile[32][33];
  const int k0 = blockIdx.x << 5, n0 = blockIdx.y << 5;
  const float* ip = in + (size_t)blockIdx.z * in_hs;
  bf16* op = out + (size_t)blockIdx.z * out_hs;
  const int tx = threadIdx.x & 31, ty = threadIdx.x >> 5;
#pragma unroll
  for (int r = 0; r < 4; ++r)
    tile[ty * 4 + r][tx] = ip[(size_t)(k0 + ty * 4 + r) * N + n0 + tx];
  __syncthreads();
#pragma unroll
  for (int r = 0; r < 4; ++r)
    op[(size_t)(n0 + ty * 4 + r) * K + k0 + tx] = tobf(tile[tx][ty * 4 + r] * scale);
}

// ---------------- bias scale copy ----------------
__global__ void bscale_kernel(const float* __restrict__ in, float* __restrict__ out, int n, float s) {
  int i = blockIdx.x * 256 + threadIdx.x;
  if (i < n) out[i] = in[i] * s;
}

// =====================================================================
// GEMM: out[M][N] = A[M][K] (bf16, row-major) dot W[N][K] (bf16, row-major, = B^T)
// EPI 0: bf16 out = acc + bias
// EPI 1: f32  out = acc + bias + resid
// EPI 2: bf16 out = relu(acc + bias)
// EPI 3: bf16 V-transpose store: out[((b*16+h)*64+dk)*1024 + l]
// =====================================================================
template<int EPI>
__global__ __launch_bounds__(256, 2)
void gemm_bt(const bf16* __restrict__ A, const bf16* __restrict__ W,
             const float* __restrict__ bias, const float* __restrict__ resid,
             void* __restrict__ outv, int M, int N, int K) {
  __shared__ bf16 sA[2][128 * 64];
  __shared__ bf16 sB[2][128 * 64];
  const int nbx = N >> 7;
  const int nwg = (M >> 7) * nbx;
  int bid = (int)blockIdx.x;
  bid = (bid & 7) * (nwg >> 3) + (bid >> 3);   // XCD swizzle (nwg % 8 == 0)
  const int tm = bid / nbx, tn = bid - tm * nbx;
  const int tid = threadIdx.x;
  const int lane = tid & 63;
  const int w = tid >> 6;
  const int wm = (w >> 1) << 6, wn = (w & 1) << 6;
  const int l15 = lane & 15, l4 = lane >> 4;

  int srow[4], scol[4];
#pragma unroll
  for (int j = 0; j < 4; ++j) {
    int g = tid + (j << 8);
    srow[j] = g >> 3;
    scol[j] = ((g & 7) ^ (srow[j] & 7)) << 3;
  }
  const bf16* Abase = A + (size_t)(tm * 128) * K;
  const bf16* Bbase = W + (size_t)(tn * 128) * K;

  f32x4 acc[4][4] = {};
  const int nt = K >> 6;
  int cur = 0;

  auto stage = [&](int buf, int t) {
    const int kb = t << 6;
#pragma unroll
    for (int j = 0; j < 4; ++j) {
      int g = tid + (j << 8);
      gll16(Abase + (size_t)srow[j] * K + kb + scol[j], &sA[buf][g << 3]);
    }
#pragma unroll
    for (int j = 0; j < 4; ++j) {
      int g = tid + (j << 8);
      gll16(Bbase + (size_t)srow[j] * K + kb + scol[j], &sB[buf][g << 3]);
    }
  };

  stage(0, 0);
  __syncthreads();

  for (int t = 0; t < nt; ++t) {
    if (t + 1 < nt) stage(cur ^ 1, t + 1);
    bf16x8 af[4][2], bfm[4][2];
#pragma unroll
    for (int mi = 0; mi < 4; ++mi)
#pragma unroll
      for (int kk = 0; kk < 2; ++kk) {
        int r = wm + (mi << 4) + l15;
        int off = (r << 7) + (kk << 6) + (l4 << 4);
        off ^= (r & 7) << 4;
        af[mi][kk] = *(const bf16x8*)((const char*)sA[cur] + off);
      }
#pragma unroll
    for (int ni = 0; ni < 4; ++ni)
#pragma unroll
      for (int kk = 0; kk < 2; ++kk) {
        int r = wn + (ni << 4) + l15;
        int off = (r << 7) + (kk << 6) + (l4 << 4);
        off ^= (r & 7) << 4;
        bfm[ni][kk] = *(const bf16x8*)((const char*)sB[cur] + off);
      }
#pragma unroll
    for (int mi = 0; mi < 4; ++mi)
#pragma unroll
      for (int ni = 0; ni < 4; ++ni)
#pragma unroll
        for (int kk = 0; kk < 2; ++kk)
          acc[mi][ni] = __builtin_amdgcn_mfma_f32_16x16x32_bf16(af[mi][kk], bfm[ni][kk],
                                                                acc[mi][ni], 0, 0, 0);
    __syncthreads();
    cur ^= 1;
  }

  const int row0 = tm * 128 + wm + (l4 << 2);
  const int col0 = tn * 128 + wn + l15;
#pragma unroll
  for (int ni = 0; ni < 4; ++ni) {
    const int col = col0 + (ni << 4);
    const float bv = bias ? bias[col] : 0.f;
#pragma unroll
    for (int mi = 0; mi < 4; ++mi) {
      const int rr = row0 + (mi << 4);
      f32x4 v = acc[mi][ni];
      if (EPI == 0) {
        bf16* out = (bf16*)outv;
#pragma unroll
        for (int r = 0; r < 4; ++r) out[(size_t)(rr + r) * N + col] = tobf(v[r] + bv);
      } else if (EPI == 1) {
        float* out = (float*)outv;
#pragma unroll
        for (int r = 0; r < 4; ++r) {
          size_t idx = (size_t)(rr + r) * N + col;
          out[idx] = v[r] + bv + resid[idx];
        }
      } else if (EPI == 2) {
        bf16* out = (bf16*)outv;
#pragma unroll
        for (int r = 0; r < 4; ++r) out[(size_t)(rr + r) * N + col] = tobf(fmaxf(v[r] + bv, 0.f));
      } else { // EPI == 3: V^T store
        bf16* out = (bf16*)outv;
        const int bb = rr >> 10, l0 = rr & 1023;
        const int hh = col >> 6, dk = col & 63;
        bf16x4v pk;
#pragma unroll
        for (int r = 0; r < 4; ++r) pk[r] = tobf(v[r] + bv);
        *(bf16x4v*)(out + ((size_t)((bb * 16 + hh) * 64 + dk) << 10) + l0) = pk;
      }
    }
  }
}

// =====================================================================
// Attention: flat grid of 1024 blocks; d%128 = (b,h) so all 8 q-blocks of a
// head land on the same XCD (round-robin dispatch -> d%8 == bh%8).
// Double-buffered K/V staging, one barrier per tile. Per-wave P tile in LDS
// (no barrier needed: same-wave LDS RAW ordered by lgkmcnt).
// Softmax denominator over ALL columns (reference applies tril AFTER softmax);
// masked kernel skips V-stage/P/PV for fully-masked tiles (numerator zero).
// =====================================================================
template<bool MASKED>
__global__ __launch_bounds__(256, 3)
void attn_kernel(const bf16* __restrict__ Qp, const bf16* __restrict__ Kp,
                 const bf16* __restrict__ Vt, bf16* __restrict__ Z) {
  __shared__ bf16 sK[2][64 * 64];
  __shared__ bf16 sV[2][64 * 64];
  __shared__ bf16 sP[4][32 * 72];
  const int Lk = 1024;
  const int d = blockIdx.x;
  const int bh = d & 127, qb = d >> 7;
  const int b = bh >> 4, h = bh & 15;
  const int q0 = qb << 7;
  const int tid = threadIdx.x, lane = tid & 63, w = tid >> 6;
  const int l15 = lane & 15, l4 = lane >> 4;

  const bf16* Qb = Qp + ((size_t)(b * 1024 + q0 + w * 32)) * 1024 + h * 64;
  bf16x8 qf[2][2];
#pragma unroll
  for (int mi = 0; mi < 2; ++mi)
#pragma unroll
    for (int kk = 0; kk < 2; ++kk)
      qf[mi][kk] = *(const bf16x8*)(Qb + (size_t)((mi << 4) + l15) * 1024 + (kk << 5) + (l4 << 3));

  f32x4 o[4][2] = {};
  float Mr[2][4], Lr[2][4];
#pragma unroll
  for (int mi = 0; mi < 2; ++mi)
#pragma unroll
    for (int r = 0; r < 4; ++r) { Mr[mi][r] = -1e30f; Lr[mi][r] = 0.f; }

  const bf16* Kb = Kp + ((size_t)b * Lk) * 1024 + h * 64;
  const bf16* Vb = Vt + ((size_t)(b * 16 + h)) * 64 * Lk;

  auto stage = [&](int buf, int t, bool withV) {
    const int kv0 = t << 6;
#pragma unroll
    for (int j = 0; j < 2; ++j) {
      int g = tid + (j << 8);
      int r = g >> 3;
      int sc = ((g & 7) ^ (r & 7)) << 3;
      gll16(Kb + (size_t)(kv0 + r) * 1024 + sc, &sK[buf][g << 3]);
      if (withV) gll16(Vb + (size_t)r * Lk + kv0 + sc, &sV[buf][g << 3]);
    }
  };
  auto needPV = [&](int t) -> bool { return !MASKED || ((t << 6) < q0 + 128); };

  const int NT = Lk >> 6;
  stage(0, 0, true);
  __syncthreads();
  int cur = 0;

  for (int t = 0; t < NT; ++t) {
    if (t + 1 < NT) stage(cur ^ 1, t + 1, needPV(t + 1));
    const int kv0 = t << 6;

    // S = Q K^T (pre-scaled)
    bf16x8 kf[4][2];
#pragma unroll
    for (int n = 0; n < 4; ++n)
#pragma unroll
      for (int kk = 0; kk < 2; ++kk) {
        int r = (n << 4) + l15;
        int off = (r << 7) + (kk << 6) + (l4 << 4);
        off ^= (r & 7) << 4;
        kf[n][kk] = *(const bf16x8*)((const char*)sK[cur] + off);
      }
    f32x4 s[4][2] = {};
#pragma unroll
    for (int n = 0; n < 4; ++n)
#pragma unroll
      for (int mi = 0; mi < 2; ++mi)
#pragma unroll
        for (int kk = 0; kk < 2; ++kk)
          s[n][mi] = __builtin_amdgcn_mfma_f32_16x16x32_bf16(qf[mi][kk], kf[n][kk],
                                                             s[n][mi], 0, 0, 0);

    // online softmax (wave-parallel 16-lane butterflies; denominator unmasked)
#pragma unroll
    for (int mi = 0; mi < 2; ++mi)
#pragma unroll
      for (int r = 0; r < 4; ++r) {
        float tmx = fmaxf(fmaxf(s[0][mi][r], s[1][mi][r]), fmaxf(s[2][mi][r], s[3][mi][r]));
#pragma unroll
        for (int dd = 1; dd < 16; dd <<= 1) tmx = fmaxf(tmx, __shfl_xor(tmx, dd, 64));
        const float Mn = fmaxf(Mr[mi][r], tmx);
        const float al = __expf(Mr[mi][r] - Mn);
        float rs = 0.f;
#pragma unroll
        for (int n = 0; n < 4; ++n) {
          float p = __expf(s[n][mi][r] - Mn);
          s[n][mi][r] = p;
          rs += p;
        }
#pragma unroll
        for (int dd = 1; dd < 16; dd <<= 1) rs += __shfl_xor(rs, dd, 64);
        Lr[mi][r] = Lr[mi][r] * al + rs;
        Mr[mi][r] = Mn;
#pragma unroll
        for (int nd = 0; nd < 4; ++nd) o[nd][mi][r] *= al;
      }

    if (needPV(t)) {
      // write P (masked) to per-wave LDS [32][72]
#pragma unroll
      for (int n = 0; n < 4; ++n)
#pragma unroll
        for (int mi = 0; mi < 2; ++mi)
#pragma unroll
          for (int r = 0; r < 4; ++r) {
            float v = s[n][mi][r];
            if (MASKED) {
              int cg = kv0 + (n << 4) + l15;
              int rg = q0 + (w << 5) + (mi << 4) + (l4 << 2) + r;
              if (cg > rg) v = 0.f;
            }
            sP[w][((mi << 4) + (l4 << 2) + r) * 72 + (n << 4) + l15] = tobf(v);
          }

      // O += P V  (A = P rows q, B^T = Vt rows dk); same-wave sP, no barrier
      bf16x8 vf[4][2], pa[2][2];
#pragma unroll
      for (int nd = 0; nd < 4; ++nd)
#pragma unroll
        for (int kk = 0; kk < 2; ++kk) {
          int r = (nd << 4) + l15;
          int off = (r << 7) + (kk << 6) + (l4 << 4);
          off ^= (r & 7) << 4;
          vf[nd][kk] = *(const bf16x8*)((const char*)sV[cur] + off);
        }
#pragma unroll
      for (int mi = 0; mi < 2; ++mi)
#pragma unroll
        for (int kk = 0; kk < 2; ++kk)
          pa[mi][kk] = *(const bf16x8*)((const char*)sP[w] +
                                        ((mi << 4) + l15) * 144 + (kk << 6) + (l4 << 4));
#pragma unroll
      for (int nd = 0; nd < 4; ++nd)
#pragma unroll
        for (int mi = 0; mi < 2; ++mi)
#pragma unroll
          for (int kk = 0; kk < 2; ++kk)
            o[nd][mi] = __builtin_amdgcn_mfma_f32_16x16x32_bf16(pa[mi][kk], vf[nd][kk],
                                                                o[nd][mi], 0, 0, 0);
    }
    __syncthreads();
    cur ^= 1;
  }

  // normalize + store Z [B][L][H*64]
  float inv[2][4];
#pragma unroll
  for (int mi = 0; mi < 2; ++mi)
#pragma unroll
    for (int r = 0; r < 4; ++r) inv[mi][r] = 1.f / Lr[mi][r];
  bf16* Zb = Z + ((size_t)(b * 1024 + q0 + w * 32)) * 1024 + h * 64;
#pragma unroll
  for (int nd = 0; nd < 4; ++nd)
#pragma unroll
    for (int mi = 0; mi < 2; ++mi)
#pragma unroll
      for (int r = 0; r < 4; ++r)
        Zb[(size_t)((mi << 4) + (l4 << 2) + r) * 1024 + (nd << 4) + l15] =
            tobf(o[nd][mi][r] * inv[mi][r]);
}

// ---------------- LayerNorm over D=1024, one row per block ----------------
__global__ __launch_bounds__(256)
void ln_kernel(const float* __restrict__ in, const float* __restrict__ gw,
               const float* __restrict__ bw, float* __restrict__ outf,
               bf16* __restrict__ outb) {
  const int row = blockIdx.x, tid = threadIdx.x;
  const size_t base = (size_t)row << 10;
  const float4 v = *(const float4*)(in + base + tid * 4);
  float s = v.x + v.y + v.z + v.w;
  float ss = v.x * v.x + v.y * v.y + v.z * v.z + v.w * v.w;
#pragma unroll
  for (int d = 1; d < 64; d <<= 1) { s += __shfl_xor(s, d, 64); ss += __shfl_xor(ss, d, 64); }
  __shared__ float red[8];
  const int w = tid >> 6;
  if ((tid & 63) == 0) { red[w] = s; red[4 + w] = ss; }
  __syncthreads();
  s = red[0] + red[1] + red[2] + red[3];
  ss = red[4] + red[5] + red[6] + red[7];
  const float mu = s * (1.f / 1024.f);
  const float var = ss * (1.f / 1024.f) - mu * mu;
  const float rstd = rsqrtf(var + 1e-5f);
  const float4 g4 = *(const float4*)(gw + tid * 4);
  const float4 b4 = *(const float4*)(bw + tid * 4);
  const float o0 = (v.x - mu) * rstd * g4.x + b4.x;
  const float o1 = (v.y - mu) * rstd * g4.y + b4.y;
  const float o2 = (v.z - mu) * rstd * g4.z + b4.z;
  const float o3 = (v.w - mu) * rstd * g4.w + b4.w;
  if (outf) { float4 of; of.x = o0; of.y = o1; of.z = o2; of.w = o3;
              *(float4*)(outf + base + tid * 4) = of; }
  if (outb) { bf16x4v ob; ob[0] = tobf(o0); ob[1] = tobf(o1); ob[2] = tobf(o2); ob[3] = tobf(o3);
              *(bf16x4v*)(outb + base + tid * 4) = ob; }
}

// =====================================================================
extern "C" void kernel_launch(void* const* d_in, const int* in_sizes, int n_in,
                              void* d_out, int out_size, void* d_ws, size_t ws_size,
                              hipStream_t stream) {
  const float* x   = (const float*)d_in[0];
  const float* enc = (const float*)d_in[1];
  const float* Wq1 = (const float*)d_in[2];
  const float* bq1 = (const float*)d_in[3];
  const float* Wk1 = (const float*)d_in[4];
  const float* bk1 = (const float*)d_in[5];
  const float* Wv1 = (const float*)d_in[6];
  const float* bv1 = (const float*)d_in[7];
  const float* Wo1 = (const float*)d_in[8];
  const float* bo1 = (const float*)d_in[9];
  const float* Wq2 = (const float*)d_in[10];
  const float* bq2 = (const float*)d_in[11];
  const float* Wk2 = (const float*)d_in[12];
  const float* bk2 = (const float*)d_in[13];
  const float* Wv2 = (const float*)d_in[14];
  const float* bv2 = (const float*)d_in[15];
  const float* Wo2 = (const float*)d_in[16];
  const float* bo2 = (const float*)d_in[17];
  const float* W1  = (const float*)d_in[18];
  const float* b1  = (const float*)d_in[19];
  const float* W2  = (const float*)d_in[20];
  const float* b2  = (const float*)d_in[21];
  const float* g1  = (const float*)d_in[22];
  const float* be1 = (const float*)d_in[23];
  const float* g2  = (const float*)d_in[24];
  const float* be2 = (const float*)d_in[25];
  const float* g3  = (const float*)d_in[26];
  const float* be3 = (const float*)d_in[27];

  char* ws = (char*)d_ws;
  size_t off = 0;
  auto alloc = [&](size_t bytes) { char* p = ws + off; off += (bytes + 255) & ~(size_t)255; return p; };
  const size_t ACT = (size_t)8 * 1024 * 1024 * 2;  // 16 MB: bf16 [8192][1024]
  const size_t WSQ = (size_t)1024 * 1024 * 2;      // 2 MB

  bf16* xb    = (bf16*)alloc(ACT);
  bf16* encb  = (bf16*)alloc(ACT);
  bf16* Wq1t  = (bf16*)alloc(WSQ);
  bf16* Wk1t  = (bf16*)alloc(WSQ);
  bf16* Wv1t  = (bf16*)alloc(WSQ);
  bf16* Wq2t  = (bf16*)alloc(WSQ);
  bf16* Wk2t  = (bf16*)alloc(WSQ);
  bf16* Wv2t  = (bf16*)alloc(WSQ);
  bf16* Wo1t  = (bf16*)alloc(WSQ);
  bf16* Wo2t  = (bf16*)alloc(WSQ);
  bf16* W1t   = (bf16*)alloc((size_t)4096 * 1024 * 2);
  bf16* W2t   = (bf16*)alloc((size_t)4096 * 1024 * 2);
  float* sbq1 = (float*)alloc(4096);
  float* sbq2 = (float*)alloc(4096);
  char*  S    = alloc((size_t)64 * 1024 * 1024);
  float* rbuf = (float*)alloc((size_t)8 * 1024 * 1024 * 4);
  float* xnf  = (float*)alloc((size_t)8 * 1024 * 1024 * 4);
  bf16*  xnb  = (bf16*)alloc(ACT);

  bf16* q1   = (bf16*)(S);
  bf16* k1   = (bf16*)(S + ACT);
  bf16* vt1  = (bf16*)(S + 2 * ACT);
  bf16* z1   = (bf16*)(S + 3 * ACT);
  bf16* hbuf = (bf16*)S;  // stage 3 reuse (64 MB)

  dim3 b256(256);
  // prep: casts + weight packs
  cast_f2b_kernel<<<8192, b256, 0, stream>>>(x, xb, 2097152);
  cast_f2b_kernel<<<8192, b256, 0, stream>>>(enc, encb, 2097152);
  tpack_kernel<<<dim3(32, 2, 16), b256, 0, stream>>>(Wq1, Wq1t, 1024, 64, 65536, 65536, 0.125f);
  tpack_kernel<<<dim3(32, 2, 16), b256, 0, stream>>>(Wk1, Wk1t, 1024, 64, 65536, 65536, 1.f);
  tpack_kernel<<<dim3(32, 2, 16), b256, 0, stream>>>(Wv1, Wv1t, 1024, 64, 65536, 65536, 1.f);
  tpack_kernel<<<dim3(32, 2, 16), b256, 0, stream>>>(Wq2, Wq2t, 1024, 64, 65536, 65536, 0.125f);
  tpack_kernel<<<dim3(32, 2, 16), b256, 0, stream>>>(Wk2, Wk2t, 1024, 64, 65536, 65536, 1.f);
  tpack_kernel<<<dim3(32, 2, 16), b256, 0, stream>>>(Wv2, Wv2t, 1024, 64, 65536, 65536, 1.f);
  tpack_kernel<<<dim3(32, 32, 1), b256, 0, stream>>>(Wo1, Wo1t, 1024, 1024, 0, 0, 1.f);
  tpack_kernel<<<dim3(32, 32, 1), b256, 0, stream>>>(Wo2, Wo2t, 1024, 1024, 0, 0, 1.f);
  tpack_kernel<<<dim3(32, 128, 1), b256, 0, stream>>>(W1, W1t, 1024, 4096, 0, 0, 1.f);
  tpack_kernel<<<dim3(128, 32, 1), b256, 0, stream>>>(W2, W2t, 4096, 1024, 0, 0, 1.f);
  bscale_kernel<<<4, b256, 0, stream>>>(bq1, sbq1, 1024, 0.125f);
  bscale_kernel<<<4, b256, 0, stream>>>(bq2, sbq2, 1024, 0.125f);

  // stage 1: masked self-attention
  gemm_bt<0><<<512, b256, 0, stream>>>(xb, Wq1t, sbq1, nullptr, q1, 8192, 1024, 1024);
  gemm_bt<0><<<512, b256, 0, stream>>>(xb, Wk1t, bk1, nullptr, k1, 8192, 1024, 1024);
  gemm_bt<3><<<512, b256, 0, stream>>>(xb, Wv1t, bv1, nullptr, vt1, 8192, 1024, 1024);
  attn_kernel<true><<<1024, b256, 0, stream>>>(q1, k1, vt1, z1);
  gemm_bt<1><<<512, b256, 0, stream>>>(z1, Wo1t, bo1, x, rbuf, 8192, 1024, 1024);
  ln_kernel<<<8192, b256, 0, stream>>>(rbuf, g1, be1, xnf, xnb);

  // stage 2: cross-attention
  gemm_bt<0><<<512, b256, 0, stream>>>(xnb, Wq2t, sbq2, nullptr, q1, 8192, 1024, 1024);
  gemm_bt<0><<<512, b256, 0, stream>>>(encb, Wk2t, bk2, nullptr, k1, 8192, 1024, 1024);
  gemm_bt<3><<<512, b256, 0, stream>>>(encb, Wv2t, bv2, nullptr, vt1, 8192, 1024, 1024);
  attn_kernel<false><<<1024, b256, 0, stream>>>(q1, k1, vt1, z1);
  gemm_bt<1><<<512, b256, 0, stream>>>(z1, Wo2t, bo2, xnf, rbuf, 8192, 1024, 1024);
  ln_kernel<<<8192, b256, 0, stream>>>(rbuf, g2, be2, xnf, xnb);

  // stage 3: MLP (conv1d k=1 pair)
  gemm_bt<2><<<2048, b256, 0, stream>>>(xnb, W1t, b1, nullptr, hbuf, 8192, 4096, 1024);
  gemm_bt<1><<<512, b256, 0, stream>>>(hbuf, W2t, b2, xnf, rbuf, 8192, 1024, 4096);
  ln_kernel<<<8192, b256, 0, stream>>>(rbuf, g3, be3, (float*)d_out, nullptr);
}